// Round 13
// baseline (193.002 us; speedup 1.0000x reference)
//
#include <hip/hip_runtime.h>

#define NS 256
#define NW 128
#define NH 768
#define NL 384          // TOPK*W keys
#define WH (NW*NH)      // 98304
#define OUTROWS 127

typedef __attribute__((ext_vector_type(8))) short short8;
typedef __attribute__((ext_vector_type(8))) unsigned short ushort8;
typedef __attribute__((ext_vector_type(8))) __bf16 bf16x8;
typedef __attribute__((ext_vector_type(4))) float f32x4;

#define XS_STRIDE 72          // QK: [384][72] bf16 (144B rows; r5-proven conflict-free)
#define PS_STRIDE 392         // Ps [128][392] bf16, XOR-swizzled rows
#define SMEM_PS   55296       // = 384*72*2; Ps after QK's Xs
#define SMEM_RED  (SMEM_PS + 128*PS_STRIDE*2)   // 155648
#define SMEM_TOTAL (SMEM_RED + 4096)            // 159744 <= 163840

// barrier WITHOUT vmcnt drain: orders LDS only; in-flight global->reg loads survive
// (correctness proven r6/r7)
#define BAR() do { asm volatile("s_waitcnt lgkmcnt(0)" ::: "memory"); \
                   __builtin_amdgcn_s_barrier(); } while (0)

__device__ __forceinline__ unsigned short bf16b(float f) {   // sw RNE (cold path)
  union { float f; unsigned u; } x; x.f = f;
  return (unsigned short)((x.u + 0x7fffu + ((x.u >> 16) & 1u)) >> 16);
}
__device__ __forceinline__ float b2f(unsigned short h) {
  union { unsigned u; float f; } x; x.u = ((unsigned)h) << 16;
  return x.f;
}
__device__ __forceinline__ unsigned short bfc(float f) {     // hw cvt (RNE)
  __bf16 h = (__bf16)f;
  return __builtin_bit_cast(unsigned short, h);
}

// ---- prelude, ONE launch: top3 (blk 0..255) + PE table (256..543) + bf16 precast (544..3615) ----
__global__ __launch_bounds__(1024) void k_pre(const float* __restrict__ inp,
                                              int* __restrict__ idxw,
                                              unsigned short* __restrict__ peb,
                                              unsigned short* __restrict__ inpb) {
  const int t = threadIdx.x;
  const int b = blockIdx.x;
  if (b >= 544) {               // bf16 precast: 3072 blocks x 8192 elems
    size_t base = ((size_t)(b - 544) * 1024 + t) * 8;
    float4 a = *(const float4*)(inp + base);
    float4 c = *(const float4*)(inp + base + 4);
    ushort8 o;
    o[0] = bfc(a.x); o[1] = bfc(a.y); o[2] = bfc(a.z); o[3] = bfc(a.w);
    o[4] = bfc(c.x); o[5] = bfc(c.y); o[6] = bfc(c.z); o[7] = bfc(c.w);
    *(ushort8*)(inpb + base) = o;
    return;
  }
  if (b >= NS) {                // PE table: 288 blocks cover 384*768
    int gid = (b - NS) * 1024 + t;
    int l = gid / NH, d = gid - l * NH;
    const float c = -0.011992630687355995f;      // (float)(-log(1e4)/768)
    float dv = __expf((float)(d & ~1) * c);
    float ang = (float)l * dv;
    float v = (d & 1) ? cosf(ang) : sinf(ang);
    peb[gid] = bf16b(v);
    return;
  }
  const int i = b;              // top-3 NN (stable, smallest-index ties)
  __shared__ float xi[772];                   // 4 segs of 193 (192 + 1 pad)
  __shared__ float dist[NS];
  __shared__ unsigned long long wkeys[16];
  for (int h = t; h < NH; h += 1024) xi[h + h / 192] = inp[(size_t)i * WH + h];
  __syncthreads();
  const int c = t >> 2, seg = t & 3;
  const float* __restrict__ row = inp + (size_t)c * WH + seg * 192;
  const float* xis = xi + seg * 193;
  float s = 0.f;
  #pragma unroll 4
  for (int h = 0; h < 192; h += 4) {
    float4 v = *(const float4*)(row + h);
    s += fabsf(xis[h]     - v.x) + fabsf(xis[h + 1] - v.y)
       + fabsf(xis[h + 2] - v.z) + fabsf(xis[h + 3] - v.w);
  }
  s += __shfl_xor(s, 1, 64);
  s += __shfl_xor(s, 2, 64);
  if (seg == 0) dist[c] = s;
  __syncthreads();
  for (int k = 0; k < 3; ++k) {
    float d = (t < NS) ? dist[t] : 3.4e38f;
    unsigned long long key = ((unsigned long long)__float_as_uint(d) << 32) | (unsigned)t;
    #pragma unroll
    for (int dd = 1; dd < 64; dd <<= 1) {
      unsigned long long o = __shfl_xor(key, dd, 64);
      key = (o < key) ? o : key;
    }
    if ((t & 63) == 0) wkeys[t >> 6] = key;
    __syncthreads();
    if (t == 0) {
      unsigned long long best = wkeys[0];
      for (int w = 1; w < 16; ++w) if (wkeys[w] < best) best = wkeys[w];
      int bj = (int)(best & 0xffffffffu);
      idxw[i * 3 + k] = bj;
      dist[bj] = 3.4e38f;
    }
    __syncthreads();
  }
}

// ---- fused attention: one block per s, 8 waves, T14 async-STAGE prefetch ----
// 156KB LDS -> 1 block/CU = 2 waves/SIMD -> 256 VGPR free; waves_per_eu(2,2)
// unlocks the budget (default heuristic capped 128 and spilled in r6).
__global__ __launch_bounds__(512) __attribute__((amdgpu_waves_per_eu(2, 2)))
void k_attn(const unsigned short* __restrict__ inpb, const unsigned short* __restrict__ peb,
            const int* __restrict__ idxw, float* __restrict__ out) {
  extern __shared__ char smem[];
  unsigned short* Xs = (unsigned short*)smem;              // QK: [384][72]; PV: VT [64][392]
  unsigned short* Ps = (unsigned short*)(smem + SMEM_PS);  // [128][392] normalized P (swizzled)
  float* red1 = (float*)(smem + SMEM_RED);                 // [128][4]
  float* red2 = red1 + 512;                                // [128][4]

  const int s = blockIdx.x;
  const int tid = threadIdx.x;
  const int lane = tid & 63, wid = tid >> 6;
  const int lrow = lane & 15, lhi = lane >> 4;
  const int i0 = idxw[s * 3 + 0], i1 = idxw[s * 3 + 1], i2 = idxw[s * 3 + 2];

  const f32x4 fz = {0.f, 0.f, 0.f, 0.f};
  f32x4 acc[4][6];
  #pragma unroll
  for (int qs = 0; qs < 4; ++qs)
    #pragma unroll
    for (int kf = 0; kf < 6; ++kf) acc[qs][kf] = fz;

  const int qh = wid & 1, kq = wid >> 1;   // QK tiling: 64q x 96k per wave
  const int rl0 = tid >> 3, c8 = (tid & 7) * 8;

  // ============ QK^T: 12 h-chunks of 64, x+pe prefetched one chunk ahead ============
  ushort8 qx[6], qp[6];
  #pragma unroll
  for (int it = 0; it < 6; ++it) {
    const int src = (it < 2) ? i0 : (it < 4 ? i1 : i2);
    const int rl = rl0 + (it & 1) * 64;
    const int r  = rl + (it >> 1) * 128;
    qx[it] = *(const ushort8*)&inpb[(size_t)src * WH + (size_t)rl * NH + c8];
    qp[it] = *(const ushort8*)&peb[r * NH + c8];
  }
  for (int hc = 0; hc < 12; ++hc) {
    const int h0 = hc * 64;
    #pragma unroll
    for (int it = 0; it < 6; ++it) {
      const int rl = rl0 + (it & 1) * 64;
      const int r  = rl + (it >> 1) * 128;
      ushort8 xv = qx[it], pv = qp[it];
      if (hc < 11) {   // issue next chunk's loads; they fly across the BARs
        const int src = (it < 2) ? i0 : (it < 4 ? i1 : i2);
        qx[it] = *(const ushort8*)&inpb[(size_t)src * WH + (size_t)rl * NH + h0 + 64 + c8];
        qp[it] = *(const ushort8*)&peb[r * NH + h0 + 64 + c8];
      }
      bf16x8 o;
      #pragma unroll
      for (int j = 0; j < 8; ++j) o[j] = (__bf16)(b2f(xv[j]) + b2f(pv[j]));
      *reinterpret_cast<bf16x8*>(&Xs[r * XS_STRIDE + c8]) = o;
    }
    BAR();
    __builtin_amdgcn_s_setprio(1);
    #pragma unroll
    for (int ks = 0; ks < 64; ks += 32) {
      short8 a[4];
      #pragma unroll
      for (int qs = 0; qs < 4; ++qs)
        a[qs] = *reinterpret_cast<const short8*>(&Xs[(qh * 64 + qs * 16 + lrow) * XS_STRIDE + ks + lhi * 8]);
      #pragma unroll
      for (int kf = 0; kf < 6; ++kf) {
        short8 b = *reinterpret_cast<const short8*>(&Xs[(kq * 96 + kf * 16 + lrow) * XS_STRIDE + ks + lhi * 8]);
        #pragma unroll
        for (int qs = 0; qs < 4; ++qs)
          acc[qs][kf] = __builtin_amdgcn_mfma_f32_16x16x32_bf16(a[qs], b, acc[qs][kf], 0, 0, 0);
      }
    }
    __builtin_amdgcn_s_setprio(0);
    BAR();
  }

  // ---- issue PV tile-0 prefetch NOW; softmax hides its latency ----
  ushort8 vx[6], vp[6];
  #pragma unroll
  for (int it = 0; it < 6; ++it) {
    const int src = (it < 2) ? i0 : (it < 4 ? i1 : i2);
    const int ml = rl0 + (it & 1) * 64;
    const int m  = ml + (it >> 1) * 128;
    vx[it] = *(const ushort8*)&inpb[(size_t)src * WH + (size_t)ml * NH + c8];
    vp[it] = *(const ushort8*)&peb[m * NH + c8];
  }

  // ============ softmax (rows split across 4 kq-waves; r8-proven) ============
  const float scale = 0.03608439182435161f;  // 1/sqrt(768)
  float mx[4][4];
  #pragma unroll
  for (int qs = 0; qs < 4; ++qs)
    #pragma unroll
    for (int r = 0; r < 4; ++r) {
      float m = acc[qs][0][r];
      #pragma unroll
      for (int kf = 1; kf < 6; ++kf) m = fmaxf(m, acc[qs][kf][r]);
      #pragma unroll
      for (int d = 1; d < 16; d <<= 1) m = fmaxf(m, __shfl_xor(m, d, 64));
      mx[qs][r] = m;
    }
  if (lrow == 0) {
    #pragma unroll
    for (int qs = 0; qs < 4; ++qs)
      #pragma unroll
      for (int r = 0; r < 4; ++r)
        red1[(qh * 64 + qs * 16 + lhi * 4 + r) * 4 + kq] = mx[qs][r];
  }
  BAR();
  float sm[4][4];
  #pragma unroll
  for (int qs = 0; qs < 4; ++qs)
    #pragma unroll
    for (int r = 0; r < 4; ++r) {
      const int row = qh * 64 + qs * 16 + lhi * 4 + r;
      float4 m0 = *(const float4*)&red1[row * 4];
      mx[qs][r] = fmaxf(fmaxf(m0.x, m0.y), fmaxf(m0.z, m0.w));
      sm[qs][r] = 0.f;
    }
  #pragma unroll
  for (int qs = 0; qs < 4; ++qs)
    #pragma unroll
    for (int kf = 0; kf < 6; ++kf)
      #pragma unroll
      for (int r = 0; r < 4; ++r) {
        float p = __expf((acc[qs][kf][r] - mx[qs][r]) * scale);
        acc[qs][kf][r] = p;
        sm[qs][r] += p;
      }
  #pragma unroll
  for (int qs = 0; qs < 4; ++qs)
    #pragma unroll
    for (int r = 0; r < 4; ++r) {
      #pragma unroll
      for (int d = 1; d < 16; d <<= 1) sm[qs][r] += __shfl_xor(sm[qs][r], d, 64);
    }
  if (lrow == 0) {
    #pragma unroll
    for (int qs = 0; qs < 4; ++qs)
      #pragma unroll
      for (int r = 0; r < 4; ++r)
        red2[(qh * 64 + qs * 16 + lhi * 4 + r) * 4 + kq] = sm[qs][r];
  }
  BAR();
  #pragma unroll
  for (int qs = 0; qs < 4; ++qs)
    #pragma unroll
    for (int r = 0; r < 4; ++r) {
      const int row = qh * 64 + qs * 16 + lhi * 4 + r;
      float4 s0 = *(const float4*)&red2[row * 4];
      sm[qs][r] = 1.0f / ((s0.x + s0.y) + (s0.z + s0.w));
    }
  // write normalized P (bf16) -> Ps[q][m], XOR-swizzled: byte ^= ((q>>3)&7)<<4
  #pragma unroll
  for (int qs = 0; qs < 4; ++qs)
    #pragma unroll
    for (int kf = 0; kf < 6; ++kf)
      #pragma unroll
      for (int r = 0; r < 4; ++r) {
        const int row = qh * 64 + qs * 16 + lhi * 4 + r;
        const int col = kq * 96 + kf * 16 + lrow;
        *(unsigned short*)((char*)Ps + (((row * PS_STRIDE + col) * 2) ^ (((row >> 3) & 7) << 4))) =
            bfc(acc[qs][kf][r] * sm[qs][r]);
      }
  BAR();

  // ============ PV: O = P * V (r8-proven scatter + swizzle), prefetch 1 tile ahead ============
  const int qb = wid & 3, hh = wid >> 2;   // 32q x 32h per wave per h-tile
  short8 pa[2][12];
  #pragma unroll
  for (int qs = 0; qs < 2; ++qs)
    #pragma unroll
    for (int m0 = 0; m0 < 12; ++m0) {
      const int row = qb * 32 + qs * 16 + lrow;
      pa[qs][m0] = *reinterpret_cast<const short8*>(
          (const char*)Ps + (((row * PS_STRIDE + m0 * 32 + lhi * 8) * 2) ^ (((row >> 3) & 7) << 4)));
    }

  unsigned short* VT = Xs;                 // [64][392], elem-XOR ((c>>3)&7)<<3
  for (int t4 = 0; t4 < 12; ++t4) {
    const int h0 = t4 * 64;
    #pragma unroll
    for (int it = 0; it < 6; ++it) {
      const int ml = rl0 + (it & 1) * 64;
      const int m  = ml + (it >> 1) * 128;
      ushort8 xv = vx[it], pv = vp[it];
      if (t4 < 11) {
        const int src = (it < 2) ? i0 : (it < 4 ? i1 : i2);
        vx[it] = *(const ushort8*)&inpb[(size_t)src * WH + (size_t)ml * NH + h0 + 64 + c8];
        vp[it] = *(const ushort8*)&peb[m * NH + h0 + 64 + c8];
      }
      #pragma unroll
      for (int j = 0; j < 8; ++j) {
        const int vr = c8 + j;
        VT[((vr * PS_STRIDE) + m) ^ (((vr >> 3) & 7) << 3)] = bfc(b2f(xv[j]) + b2f(pv[j]));
      }
    }
    BAR();
    __builtin_amdgcn_s_setprio(1);
    f32x4 o00 = fz, o01 = fz, o10 = fz, o11 = fz;
    const int vr0 = hh * 32 + lrow, vr1 = vr0 + 16;
    const int sw0 = ((vr0 >> 3) & 7) << 4, sw1 = ((vr1 >> 3) & 7) << 4;
    #pragma unroll
    for (int mm = 0; mm < 12; ++mm) {
      const int moff = (mm * 32 + lhi * 8) * 2;
      short8 b0 = *reinterpret_cast<const short8*>((const char*)VT + ((vr0 * PS_STRIDE * 2 + moff) ^ sw0));
      short8 b1 = *reinterpret_cast<const short8*>((const char*)VT + ((vr1 * PS_STRIDE * 2 + moff) ^ sw1));
      o00 = __builtin_amdgcn_mfma_f32_16x16x32_bf16(pa[0][mm], b0, o00, 0, 0, 0);
      o01 = __builtin_amdgcn_mfma_f32_16x16x32_bf16(pa[0][mm], b1, o01, 0, 0, 0);
      o10 = __builtin_amdgcn_mfma_f32_16x16x32_bf16(pa[1][mm], b0, o10, 0, 0, 0);
      o11 = __builtin_amdgcn_mfma_f32_16x16x32_bf16(pa[1][mm], b1, o11, 0, 0, 0);
    }
    __builtin_amdgcn_s_setprio(0);
    float* ob = out + (size_t)s * (OUTROWS * NH) + h0 + hh * 32 + lrow;
    #pragma unroll
    for (int qs = 0; qs < 2; ++qs)
      #pragma unroll
      for (int hf = 0; hf < 2; ++hf) {
        f32x4 o = (qs == 0) ? (hf == 0 ? o00 : o01) : (hf == 0 ? o10 : o11);
        #pragma unroll
        for (int r = 0; r < 4; ++r) {
          const int q = qb * 32 + qs * 16 + lhi * 4 + r;
          if (q < OUTROWS) ob[(size_t)q * NH + hf * 16] = o[r];
        }
      }
    BAR();
  }
}

// ---------------- launch ----------------
extern "C" void kernel_launch(void* const* d_in, const int* in_sizes, int n_in,
                              void* d_out, int out_size, void* d_ws, size_t ws_size,
                              hipStream_t stream) {
  (void)in_sizes; (void)n_in; (void)out_size; (void)ws_size;
  const float* inp = (const float*)d_in[0];
  float* out = (float*)d_out;
  char* ws = (char*)d_ws;

  unsigned short* peb = (unsigned short*)ws;                     // 589824 B
  int* idxw           = (int*)(ws + 589824);                     // 3072 B
  unsigned short* inpb= (unsigned short*)(ws + 592896);          // 50331648 B

  hipLaunchKernelGGL(k_pre, dim3(256 + 288 + 3072), dim3(1024), 0, stream,
                     inp, idxw, peb, inpb);

  hipFuncSetAttribute((const void*)k_attn,
                      hipFuncAttributeMaxDynamicSharedMemorySize, SMEM_TOTAL);
  hipLaunchKernelGGL(k_attn, dim3(256), dim3(512), SMEM_TOTAL, stream,
                     inpb, peb, idxw, out);
}

// Round 14
// 160.537 us; speedup vs baseline: 1.2022x; 1.2022x over previous
//
#include <hip/hip_runtime.h>

#define NS 256
#define NW 128
#define NH 768
#define NL 384          // TOPK*W keys
#define WH (NW*NH)      // 98304
#define OUTROWS 127

typedef __attribute__((ext_vector_type(8))) short short8;
typedef __attribute__((ext_vector_type(8))) unsigned short ushort8;
typedef __attribute__((ext_vector_type(8))) __bf16 bf16x8;
typedef __attribute__((ext_vector_type(4))) float f32x4;

#define AS1(p) ((const __attribute__((address_space(1))) void*)(p))
#define AS3(p) ((__attribute__((address_space(3))) void*)(p))

// ---- primary k_attn LDS map ----
#define QKBUF   49152         // one QK buffer: [384][64] bf16 linear (src-swizzled)
#define PS_STRIDE 392         // Ps [128][392] bf16, byte-XOR ((row>>3)&7)<<4 (r8-proven)
#define OFF_RED 100352        // red1/red2: 2x [128][4] f32
#define OFF_VT  104448        // VT [64][392] bf16, elem-XOR ((c>>3)&7)<<3 (r8-proven)
#define SMEM_PRI 154624
// ---- fallback (r8) LDS map ----
#define XS2_STRIDE 136
#define FB_SMEM_PS   55296
#define FB_SMEM_RED  (FB_SMEM_PS + 128*PS_STRIDE*2)
#define FB_SMEM_TOTAL (FB_SMEM_RED + 4096)       // 159744

__device__ __forceinline__ unsigned short bf16b(float f) {   // sw RNE (cold path)
  union { float f; unsigned u; } x; x.f = f;
  return (unsigned short)((x.u + 0x7fffu + ((x.u >> 16) & 1u)) >> 16);
}
__device__ __forceinline__ float b2f(unsigned short h) {
  union { unsigned u; float f; } x; x.u = ((unsigned)h) << 16;
  return x.f;
}
__device__ __forceinline__ unsigned short bfc(float f) {     // hw cvt (RNE)
  __bf16 h = (__bf16)f;
  return __builtin_bit_cast(unsigned short, h);
}

// ---- launch 1: top3 (blk 0..255) + PE table (256..543) ----
__global__ __launch_bounds__(1024) void k_pre1(const float* __restrict__ inp,
                                               int* __restrict__ idxw,
                                               unsigned short* __restrict__ peb) {
  const int t = threadIdx.x;
  const int b = blockIdx.x;
  if (b >= NS) {                // PE table: 288 blocks cover 384*768
    int gid = (b - NS) * 1024 + t;
    int l = gid / NH, d = gid - l * NH;
    const float c = -0.011992630687355995f;      // (float)(-log(1e4)/768)
    float dv = __expf((float)(d & ~1) * c);
    float ang = (float)l * dv;
    float v = (d & 1) ? cosf(ang) : sinf(ang);
    peb[gid] = bf16b(v);
    return;
  }
  const int i = b;              // top-3 NN (stable, smallest-index ties)
  __shared__ float xi[772];
  __shared__ float dist[NS];
  __shared__ unsigned long long wkeys[16];
  for (int h = t; h < NH; h += 1024) xi[h + h / 192] = inp[(size_t)i * WH + h];
  __syncthreads();
  const int c = t >> 2, seg = t & 3;
  const float* __restrict__ row = inp + (size_t)c * WH + seg * 192;
  const float* xis = xi + seg * 193;
  float s = 0.f;
  #pragma unroll 4
  for (int h = 0; h < 192; h += 4) {
    float4 v = *(const float4*)(row + h);
    s += fabsf(xis[h]     - v.x) + fabsf(xis[h + 1] - v.y)
       + fabsf(xis[h + 2] - v.z) + fabsf(xis[h + 3] - v.w);
  }
  s += __shfl_xor(s, 1, 64);
  s += __shfl_xor(s, 2, 64);
  if (seg == 0) dist[c] = s;
  __syncthreads();
  for (int k = 0; k < 3; ++k) {
    float d = (t < NS) ? dist[t] : 3.4e38f;
    unsigned long long key = ((unsigned long long)__float_as_uint(d) << 32) | (unsigned)t;
    #pragma unroll
    for (int dd = 1; dd < 64; dd <<= 1) {
      unsigned long long o = __shfl_xor(key, dd, 64);
      key = (o < key) ? o : key;
    }
    if ((t & 63) == 0) wkeys[t >> 6] = key;
    __syncthreads();
    if (t == 0) {
      unsigned long long best = wkeys[0];
      for (int w = 1; w < 16; ++w) if (wkeys[w] < best) best = wkeys[w];
      int bj = (int)(best & 0xffffffffu);
      idxw[i * 3 + k] = bj;
      dist[bj] = 3.4e38f;
    }
    __syncthreads();
  }
}

// ---- launch 2 (primary): xpe3[slab][src][rl][h] = bf16(x[src][rl][h] + pe[slab*128+rl][h]) ----
__global__ __launch_bounds__(1024) void k_pc3(const float* __restrict__ inp,
                                              const unsigned short* __restrict__ peb,
                                              unsigned short* __restrict__ xpe) {
  const size_t gid = (size_t)blockIdx.x * 1024 + threadIdx.x;   // 9216*1024 threads
  const int row = (int)(gid / 96);            // 0..98303 (3*256*128)
  const int w8  = (int)(gid - (size_t)row * 96) * 8;
  const int slab = row >> 15, src = (row >> 7) & 255, rl = row & 127;
  const float* px = inp + ((size_t)src * 128 + rl) * NH + w8;
  float4 a = *(const float4*)px;
  float4 b = *(const float4*)(px + 4);
  ushort8 pv = *(const ushort8*)&peb[(slab * 128 + rl) * NH + w8];
  ushort8 o;
  o[0] = bfc(a.x + b2f(pv[0])); o[1] = bfc(a.y + b2f(pv[1]));
  o[2] = bfc(a.z + b2f(pv[2])); o[3] = bfc(a.w + b2f(pv[3]));
  o[4] = bfc(b.x + b2f(pv[4])); o[5] = bfc(b.y + b2f(pv[5]));
  o[6] = bfc(b.z + b2f(pv[6])); o[7] = bfc(b.w + b2f(pv[7]));
  *(ushort8*)(xpe + gid * 8) = o;
}

// ---- fallback precast (r8): inpb = bf16(x) + separate peb, plus top3/pe ----
__global__ __launch_bounds__(1024) void k_pre_fb(const float* __restrict__ inp,
                                                 unsigned short* __restrict__ inpb) {
  size_t base = ((size_t)blockIdx.x * 1024 + threadIdx.x) * 8;   // 3072 blocks
  float4 a = *(const float4*)(inp + base);
  float4 c = *(const float4*)(inp + base + 4);
  ushort8 o;
  o[0] = bfc(a.x); o[1] = bfc(a.y); o[2] = bfc(a.z); o[3] = bfc(a.w);
  o[4] = bfc(c.x); o[5] = bfc(c.y); o[6] = bfc(c.z); o[7] = bfc(c.w);
  *(ushort8*)(inpb + base) = o;
}

// ==== PRIMARY fused attention: async QK staging via global_load_lds ====
// QK: dbuf [2][384][64] linear; global SOURCE pre-swizzled (chunk ^= row&7), frag
// reads apply matching XOR (rule: both-sides-or-neither). Staging has ZERO VALU
// and ZERO ds-ops; counted vmcnt(6) + raw barriers keep next chunk in flight.
__global__ __launch_bounds__(512)
void k_attn(const unsigned short* __restrict__ xpe, const int* __restrict__ idxw,
            float* __restrict__ out) {
  extern __shared__ char smem[];
  unsigned short* Ps = (unsigned short*)smem;              // [128][392] (overlays QK dbuf)
  float* red1 = (float*)(smem + OFF_RED);                  // [128][4]
  float* red2 = red1 + 512;                                // [128][4]
  unsigned short* VT = (unsigned short*)(smem + OFF_VT);   // [64][392]

  const int s = blockIdx.x;
  const int tid = threadIdx.x;
  const int lane = tid & 63, wid = tid >> 6;
  const int lrow = lane & 15, lhi = lane >> 4;
  int idx3[3];
  idx3[0] = idxw[s * 3 + 0]; idx3[1] = idxw[s * 3 + 1]; idx3[2] = idxw[s * 3 + 2];

  const f32x4 fz = {0.f, 0.f, 0.f, 0.f};
  f32x4 acc[4][6];
  #pragma unroll
  for (int qs = 0; qs < 4; ++qs)
    #pragma unroll
    for (int kf = 0; kf < 6; ++kf) acc[qs][kf] = fz;

  const int qh = wid & 1, kq = wid >> 1;     // 64q x 96k per wave
  const int irow0 = wid * 48;                // wave's staging row base
  const int lr8 = lane >> 3, lslot = lane & 7;

  // ---- async stage one 64-wide h-chunk into buf ----
  auto issue = [&](int buf, int h0) {
    #pragma unroll
    for (int i = 0; i < 6; ++i) {
      const int row = irow0 + i * 8 + lr8;               // 0..383 (8-row granule, slab-uniform)
      const int slab = row >> 7, rl = row & 127;
      const int cg = lslot ^ (row & 7);                  // source pre-swizzle
      const unsigned short* g = xpe +
          (((size_t)slab * 256 + idx3[slab]) * 128 + rl) * (size_t)NH + h0 + cg * 8;
      __builtin_amdgcn_global_load_lds(AS1(g), AS3(smem + buf * QKBUF + (irow0 + i * 8) * 128),
                                       16, 0, 0);
    }
  };

  // ============ QK^T: 12 chunks, double-buffered async staging ============
  issue(0, 0);
  for (int hc = 0; hc < 12; ++hc) {
    const int cur = hc & 1;
    if (hc < 11) {
      issue(cur ^ 1, (hc + 1) * 64);
      asm volatile("s_waitcnt vmcnt(6)" ::: "memory");   // own 6 for cur landed; next 6 fly
    } else {
      asm volatile("s_waitcnt vmcnt(0)" ::: "memory");
    }
    __builtin_amdgcn_s_barrier();
    const unsigned short* Xc = (const unsigned short*)(smem + cur * QKBUF);
    __builtin_amdgcn_s_setprio(1);
    #pragma unroll
    for (int ks = 0; ks < 64; ks += 32) {
      short8 a[4];
      #pragma unroll
      for (int qs = 0; qs < 4; ++qs) {
        const int ar = qh * 64 + qs * 16 + lrow;
        a[qs] = *reinterpret_cast<const short8*>(
            &Xc[ar * 64 + ((((ks >> 3) + lhi) ^ (ar & 7)) << 3)]);
      }
      #pragma unroll
      for (int kf = 0; kf < 6; ++kf) {
        const int br = kq * 96 + kf * 16 + lrow;
        short8 b = *reinterpret_cast<const short8*>(
            &Xc[br * 64 + ((((ks >> 3) + lhi) ^ (br & 7)) << 3)]);
        #pragma unroll
        for (int qs = 0; qs < 4; ++qs)
          acc[qs][kf] = __builtin_amdgcn_mfma_f32_16x16x32_bf16(a[qs], b, acc[qs][kf], 0, 0, 0);
      }
    }
    __builtin_amdgcn_s_setprio(0);
    __builtin_amdgcn_s_barrier();
  }

  // ============ softmax (r8-proven) ============
  const float scale = 0.03608439182435161f;  // 1/sqrt(768)
  float mx[4][4];
  #pragma unroll
  for (int qs = 0; qs < 4; ++qs)
    #pragma unroll
    for (int r = 0; r < 4; ++r) {
      float m = acc[qs][0][r];
      #pragma unroll
      for (int kf = 1; kf < 6; ++kf) m = fmaxf(m, acc[qs][kf][r]);
      #pragma unroll
      for (int d = 1; d < 16; d <<= 1) m = fmaxf(m, __shfl_xor(m, d, 64));
      mx[qs][r] = m;
    }
  if (lrow == 0) {
    #pragma unroll
    for (int qs = 0; qs < 4; ++qs)
      #pragma unroll
      for (int r = 0; r < 4; ++r)
        red1[(qh * 64 + qs * 16 + lhi * 4 + r) * 4 + kq] = mx[qs][r];
  }
  __syncthreads();
  float sm[4][4];
  #pragma unroll
  for (int qs = 0; qs < 4; ++qs)
    #pragma unroll
    for (int r = 0; r < 4; ++r) {
      const int row = qh * 64 + qs * 16 + lhi * 4 + r;
      float4 m0 = *(const float4*)&red1[row * 4];
      mx[qs][r] = fmaxf(fmaxf(m0.x, m0.y), fmaxf(m0.z, m0.w));
      sm[qs][r] = 0.f;
    }
  #pragma unroll
  for (int qs = 0; qs < 4; ++qs)
    #pragma unroll
    for (int kf = 0; kf < 6; ++kf)
      #pragma unroll
      for (int r = 0; r < 4; ++r) {
        float p = __expf((acc[qs][kf][r] - mx[qs][r]) * scale);
        acc[qs][kf][r] = p;
        sm[qs][r] += p;
      }
  #pragma unroll
  for (int qs = 0; qs < 4; ++qs)
    #pragma unroll
    for (int r = 0; r < 4; ++r) {
      #pragma unroll
      for (int d = 1; d < 16; d <<= 1) sm[qs][r] += __shfl_xor(sm[qs][r], d, 64);
    }
  if (lrow == 0) {
    #pragma unroll
    for (int qs = 0; qs < 4; ++qs)
      #pragma unroll
      for (int r = 0; r < 4; ++r)
        red2[(qh * 64 + qs * 16 + lhi * 4 + r) * 4 + kq] = sm[qs][r];
  }
  __syncthreads();
  #pragma unroll
  for (int qs = 0; qs < 4; ++qs)
    #pragma unroll
    for (int r = 0; r < 4; ++r) {
      const int row = qh * 64 + qs * 16 + lhi * 4 + r;
      float4 s0 = *(const float4*)&red2[row * 4];
      sm[qs][r] = 1.0f / ((s0.x + s0.y) + (s0.z + s0.w));
    }
  // normalized P -> Ps (overlays dead QK dbuf), byte-XOR ((row>>3)&7)<<4
  #pragma unroll
  for (int qs = 0; qs < 4; ++qs)
    #pragma unroll
    for (int kf = 0; kf < 6; ++kf)
      #pragma unroll
      for (int r = 0; r < 4; ++r) {
        const int row = qh * 64 + qs * 16 + lhi * 4 + r;
        const int col = kq * 96 + kf * 16 + lrow;
        *(unsigned short*)((char*)Ps + (((row * PS_STRIDE + col) * 2) ^ (((row >> 3) & 7) << 4))) =
            bfc(acc[qs][kf][r] * sm[qs][r]);
      }
  __syncthreads();

  // ============ PV (r8-proven scatter; xpe source = no pe work) ============
  const int qb = wid & 3, hh = wid >> 2;
  short8 pa[2][12];
  #pragma unroll
  for (int qs = 0; qs < 2; ++qs)
    #pragma unroll
    for (int m0 = 0; m0 < 12; ++m0) {
      const int row = qb * 32 + qs * 16 + lrow;
      pa[qs][m0] = *reinterpret_cast<const short8*>(
          (const char*)Ps + (((row * PS_STRIDE + m0 * 32 + lhi * 8) * 2) ^ (((row >> 3) & 7) << 4)));
    }
  const int rl0 = tid >> 3, c8 = (tid & 7) * 8;
  for (int t4 = 0; t4 < 12; ++t4) {
    const int h0 = t4 * 64;
    #pragma unroll
    for (int it = 0; it < 6; ++it) {
      const int slab = it >> 1;
      const int ml = rl0 + (it & 1) * 64;
      const int m  = ml + slab * 128;
      ushort8 xv = *(const ushort8*)&xpe[(((size_t)slab * 256 + idx3[slab]) * 128 + ml) * (size_t)NH + h0 + c8];
      #pragma unroll
      for (int j = 0; j < 8; ++j) {
        const int vr = c8 + j;
        VT[((vr * PS_STRIDE) + m) ^ (((vr >> 3) & 7) << 3)] = xv[j];
      }
    }
    __syncthreads();
    __builtin_amdgcn_s_setprio(1);
    f32x4 o00 = fz, o01 = fz, o10 = fz, o11 = fz;
    const int vr0 = hh * 32 + lrow, vr1 = vr0 + 16;
    const int sw0 = ((vr0 >> 3) & 7) << 4, sw1 = ((vr1 >> 3) & 7) << 4;
    #pragma unroll
    for (int mm = 0; mm < 12; ++mm) {
      const int moff = (mm * 32 + lhi * 8) * 2;
      short8 b0 = *reinterpret_cast<const short8*>((const char*)VT + ((vr0 * PS_STRIDE * 2 + moff) ^ sw0));
      short8 b1 = *reinterpret_cast<const short8*>((const char*)VT + ((vr1 * PS_STRIDE * 2 + moff) ^ sw1));
      o00 = __builtin_amdgcn_mfma_f32_16x16x32_bf16(pa[0][mm], b0, o00, 0, 0, 0);
      o01 = __builtin_amdgcn_mfma_f32_16x16x32_bf16(pa[0][mm], b1, o01, 0, 0, 0);
      o10 = __builtin_amdgcn_mfma_f32_16x16x32_bf16(pa[1][mm], b0, o10, 0, 0, 0);
      o11 = __builtin_amdgcn_mfma_f32_16x16x32_bf16(pa[1][mm], b1, o11, 0, 0, 0);
    }
    __builtin_amdgcn_s_setprio(0);
    float* ob = out + (size_t)s * (OUTROWS * NH) + h0 + hh * 32 + lrow;
    #pragma unroll
    for (int qs = 0; qs < 2; ++qs)
      #pragma unroll
      for (int hf = 0; hf < 2; ++hf) {
        f32x4 o = (qs == 0) ? (hf == 0 ? o00 : o01) : (hf == 0 ? o10 : o11);
        #pragma unroll
        for (int r = 0; r < 4; ++r) {
          const int q = qb * 32 + qs * 16 + lhi * 4 + r;
          if (q < OUTROWS) ob[(size_t)q * NH + hf * 16] = o[r];
        }
      }
    __syncthreads();
  }
}

// ==== FALLBACK fused attention: r8 verbatim (inpb + peb) ====
__global__ __launch_bounds__(512)
void k_attn_fb(const unsigned short* __restrict__ inpb, const unsigned short* __restrict__ peb,
               const int* __restrict__ idxw, float* __restrict__ out) {
  extern __shared__ char smem[];
  unsigned short* Xs = (unsigned short*)smem;
  unsigned short* Ps = (unsigned short*)(smem + FB_SMEM_PS);
  float* red1 = (float*)(smem + FB_SMEM_RED);
  float* red2 = red1 + 512;

  const int s = blockIdx.x;
  const int tid = threadIdx.x;
  const int lane = tid & 63, wid = tid >> 6;
  const int lrow = lane & 15, lhi = lane >> 4;
  const int i0 = idxw[s * 3 + 0], i1 = idxw[s * 3 + 1], i2 = idxw[s * 3 + 2];

  const f32x4 fz = {0.f, 0.f, 0.f, 0.f};
  f32x4 acc[4][6];
  #pragma unroll
  for (int qs = 0; qs < 4; ++qs)
    #pragma unroll
    for (int kf = 0; kf < 6; ++kf) acc[qs][kf] = fz;

  const int qh = wid & 1, kq = wid >> 1;
  for (int hc = 0; hc < 6; ++hc) {
    const int h0 = hc * 128;
    #pragma unroll
    for (int it = 0; it < 12; ++it) {
      const int src = (it < 4) ? i0 : (it < 8 ? i1 : i2);
      const int rls = (it & 3) * 32 + (tid >> 4);
      const int r   = it * 32 + (tid >> 4);
      const int cc  = (tid & 15) * 8;
      ushort8 xv = *(const ushort8*)&inpb[(size_t)src * WH + (size_t)rls * NH + h0 + cc];
      ushort8 pv = *(const ushort8*)&peb[r * NH + h0 + cc];
      bf16x8 o;
      #pragma unroll
      for (int j = 0; j < 8; ++j) o[j] = (__bf16)(b2f(xv[j]) + b2f(pv[j]));
      *reinterpret_cast<bf16x8*>(&Xs[r * XS2_STRIDE + cc]) = o;
    }
    __syncthreads();
    __builtin_amdgcn_s_setprio(1);
    #pragma unroll
    for (int ks = 0; ks < 128; ks += 32) {
      short8 a[4];
      #pragma unroll
      for (int qs = 0; qs < 4; ++qs)
        a[qs] = *reinterpret_cast<const short8*>(&Xs[(qh * 64 + qs * 16 + lrow) * XS2_STRIDE + ks + lhi * 8]);
      #pragma unroll
      for (int kf = 0; kf < 6; ++kf) {
        short8 b = *reinterpret_cast<const short8*>(&Xs[(kq * 96 + kf * 16 + lrow) * XS2_STRIDE + ks + lhi * 8]);
        #pragma unroll
        for (int qs = 0; qs < 4; ++qs)
          acc[qs][kf] = __builtin_amdgcn_mfma_f32_16x16x32_bf16(a[qs], b, acc[qs][kf], 0, 0, 0);
      }
    }
    __builtin_amdgcn_s_setprio(0);
    __syncthreads();
  }
  const float scale = 0.03608439182435161f;
  float mx[4][4];
  #pragma unroll
  for (int qs = 0; qs < 4; ++qs)
    #pragma unroll
    for (int r = 0; r < 4; ++r) {
      float m = acc[qs][0][r];
      #pragma unroll
      for (int kf = 1; kf < 6; ++kf) m = fmaxf(m, acc[qs][kf][r]);
      #pragma unroll
      for (int d = 1; d < 16; d <<= 1) m = fmaxf(m, __shfl_xor(m, d, 64));
      mx[qs][r] = m;
    }
  if (lrow == 0) {
    #pragma unroll
    for (int qs = 0; qs < 4; ++qs)
      #pragma unroll
      for (int r = 0; r < 4; ++r)
        red1[(qh * 64 + qs * 16 + lhi * 4 + r) * 4 + kq] = mx[qs][r];
  }
  __syncthreads();
  float sm[4][4];
  #pragma unroll
  for (int qs = 0; qs < 4; ++qs)
    #pragma unroll
    for (int r = 0; r < 4; ++r) {
      const int row = qh * 64 + qs * 16 + lhi * 4 + r;
      float4 m0 = *(const float4*)&red1[row * 4];
      mx[qs][r] = fmaxf(fmaxf(m0.x, m0.y), fmaxf(m0.z, m0.w));
      sm[qs][r] = 0.f;
    }
  #pragma unroll
  for (int qs = 0; qs < 4; ++qs)
    #pragma unroll
    for (int kf = 0; kf < 6; ++kf)
      #pragma unroll
      for (int r = 0; r < 4; ++r) {
        float p = __expf((acc[qs][kf][r] - mx[qs][r]) * scale);
        acc[qs][kf][r] = p;
        sm[qs][r] += p;
      }
  #pragma unroll
  for (int qs = 0; qs < 4; ++qs)
    #pragma unroll
    for (int r = 0; r < 4; ++r) {
      #pragma unroll
      for (int d = 1; d < 16; d <<= 1) sm[qs][r] += __shfl_xor(sm[qs][r], d, 64);
    }
  if (lrow == 0) {
    #pragma unroll
    for (int qs = 0; qs < 4; ++qs)
      #pragma unroll
      for (int r = 0; r < 4; ++r)
        red2[(qh * 64 + qs * 16 + lhi * 4 + r) * 4 + kq] = sm[qs][r];
  }
  __syncthreads();
  #pragma unroll
  for (int qs = 0; qs < 4; ++qs)
    #pragma unroll
    for (int r = 0; r < 4; ++r) {
      const int row = qh * 64 + qs * 16 + lhi * 4 + r;
      float4 s0 = *(const float4*)&red2[row * 4];
      sm[qs][r] = 1.0f / ((s0.x + s0.y) + (s0.z + s0.w));
    }
  #pragma unroll
  for (int qs = 0; qs < 4; ++qs)
    #pragma unroll
    for (int kf = 0; kf < 6; ++kf)
      #pragma unroll
      for (int r = 0; r < 4; ++r) {
        const int row = qh * 64 + qs * 16 + lhi * 4 + r;
        const int col = kq * 96 + kf * 16 + lrow;
        *(unsigned short*)((char*)Ps + (((row * PS_STRIDE + col) * 2) ^ (((row >> 3) & 7) << 4))) =
            bfc(acc[qs][kf][r] * sm[qs][r]);
      }
  __syncthreads();
  const int qb = wid & 3, hh = wid >> 2;
  short8 pa[2][12];
  #pragma unroll
  for (int qs = 0; qs < 2; ++qs)
    #pragma unroll
    for (int m0 = 0; m0 < 12; ++m0) {
      const int row = qb * 32 + qs * 16 + lrow;
      pa[qs][m0] = *reinterpret_cast<const short8*>(
          (const char*)Ps + (((row * PS_STRIDE + m0 * 32 + lhi * 8) * 2) ^ (((row >> 3) & 7) << 4)));
    }
  unsigned short* VT = Xs;
  const int rl0 = tid >> 3, c8 = (tid & 7) * 8;
  for (int t4 = 0; t4 < 12; ++t4) {
    const int h0 = t4 * 64;
    #pragma unroll
    for (int it = 0; it < 6; ++it) {
      const int src = (it < 2) ? i0 : (it < 4 ? i1 : i2);
      const int ml = rl0 + (it & 1) * 64;
      const int m  = ml + (it >> 1) * 128;
      ushort8 xv = *(const ushort8*)&inpb[(size_t)src * WH + (size_t)ml * NH + h0 + c8];
      ushort8 pv = *(const ushort8*)&peb[m * NH + h0 + c8];
      #pragma unroll
      for (int j = 0; j < 8; ++j) {
        const int vr = c8 + j;
        VT[((vr * PS_STRIDE) + m) ^ (((vr >> 3) & 7) << 3)] = bfc(b2f(xv[j]) + b2f(pv[j]));
      }
    }
    __syncthreads();
    __builtin_amdgcn_s_setprio(1);
    f32x4 o00 = fz, o01 = fz, o10 = fz, o11 = fz;
    const int vr0 = hh * 32 + lrow, vr1 = vr0 + 16;
    const int sw0 = ((vr0 >> 3) & 7) << 4, sw1 = ((vr1 >> 3) & 7) << 4;
    #pragma unroll
    for (int mm = 0; mm < 12; ++mm) {
      const int moff = (mm * 32 + lhi * 8) * 2;
      short8 b0 = *reinterpret_cast<const short8*>((const char*)VT + ((vr0 * PS_STRIDE * 2 + moff) ^ sw0));
      short8 b1 = *reinterpret_cast<const short8*>((const char*)VT + ((vr1 * PS_STRIDE * 2 + moff) ^ sw1));
      o00 = __builtin_amdgcn_mfma_f32_16x16x32_bf16(pa[0][mm], b0, o00, 0, 0, 0);
      o01 = __builtin_amdgcn_mfma_f32_16x16x32_bf16(pa[0][mm], b1, o01, 0, 0, 0);
      o10 = __builtin_amdgcn_mfma_f32_16x16x32_bf16(pa[1][mm], b0, o10, 0, 0, 0);
      o11 = __builtin_amdgcn_mfma_f32_16x16x32_bf16(pa[1][mm], b1, o11, 0, 0, 0);
    }
    __builtin_amdgcn_s_setprio(0);
    float* ob = out + (size_t)s * (OUTROWS * NH) + h0 + hh * 32 + lrow;
    #pragma unroll
    for (int qs = 0; qs < 2; ++qs)
      #pragma unroll
      for (int hf = 0; hf < 2; ++hf) {
        f32x4 o = (qs == 0) ? (hf == 0 ? o00 : o01) : (hf == 0 ? o10 : o11);
        #pragma unroll
        for (int r = 0; r < 4; ++r) {
          const int q = qb * 32 + qs * 16 + lhi * 4 + r;
          if (q < OUTROWS) ob[(size_t)q * NH + hf * 16] = o[r];
        }
      }
    __syncthreads();
  }
}

// ---------------- launch ----------------
extern "C" void kernel_launch(void* const* d_in, const int* in_sizes, int n_in,
                              void* d_out, int out_size, void* d_ws, size_t ws_size,
                              hipStream_t stream) {
  (void)in_sizes; (void)n_in; (void)out_size;
  const float* inp = (const float*)d_in[0];
  float* out = (float*)d_out;
  char* ws = (char*)d_ws;

  unsigned short* peb = (unsigned short*)ws;                     // 589824 B
  int* idxw           = (int*)(ws + 589824);                     // 3072 B
  unsigned short* big = (unsigned short*)(ws + 592896);          // xpe3 (151MB) or inpb (50MB)
  const bool primary = ws_size >= (size_t)592896 + (size_t)150994944;

  hipLaunchKernelGGL(k_pre1, dim3(544), dim3(1024), 0, stream, inp, idxw, peb);

  if (primary) {
    hipLaunchKernelGGL(k_pc3, dim3(9216), dim3(1024), 0, stream, inp, peb, big);
    hipFuncSetAttribute((const void*)k_attn,
                        hipFuncAttributeMaxDynamicSharedMemorySize, SMEM_PRI);
    hipLaunchKernelGGL(k_attn, dim3(256), dim3(512), SMEM_PRI, stream, big, idxw, out);
  } else {
    hipLaunchKernelGGL(k_pre_fb, dim3(3072), dim3(1024), 0, stream, inp, big);
    hipFuncSetAttribute((const void*)k_attn_fb,
                        hipFuncAttributeMaxDynamicSharedMemorySize, FB_SMEM_TOTAL);
    hipLaunchKernelGGL(k_attn_fb, dim3(256), dim3(512), FB_SMEM_TOTAL, stream,
                       big, peb, idxw, out);
  }
}

// Round 15
// 141.628 us; speedup vs baseline: 1.3627x; 1.1335x over previous
//
#include <hip/hip_runtime.h>

#define NS 256
#define NW 128
#define NH 768
#define NL 384          // TOPK*W keys
#define WH (NW*NH)      // 98304
#define OUTROWS 127

typedef __attribute__((ext_vector_type(8))) short short8;
typedef __attribute__((ext_vector_type(8))) unsigned short ushort8;
typedef __attribute__((ext_vector_type(8))) __bf16 bf16x8;
typedef __attribute__((ext_vector_type(4))) float f32x4;

#define AS1(p) ((const __attribute__((address_space(1))) void*)(p))
#define AS3(p) ((__attribute__((address_space(3))) void*)(p))

// ---- primary k_attn LDS map ----
#define QKBUF   49152         // one QK buffer: [384][64] bf16 linear (src-swizzled)
#define PS_STRIDE 392         // Ps [128][392] bf16, byte-XOR ((row>>3)&7)<<4
#define OFF_RED 100352        // red1/red2: 2x [128][4] f32
#define OFF_VT  104448        // VT [64][392] bf16, elem-XOR ((c>>3)&7)<<3
#define SMEM_PRI 154624
// ---- fallback (r8) LDS map ----
#define XS2_STRIDE 136
#define FB_SMEM_PS   55296
#define FB_SMEM_RED  (FB_SMEM_PS + 128*PS_STRIDE*2)
#define FB_SMEM_TOTAL (FB_SMEM_RED + 4096)       // 159744

__device__ __forceinline__ unsigned short bf16b(float f) {   // sw RNE (cold path)
  union { float f; unsigned u; } x; x.f = f;
  return (unsigned short)((x.u + 0x7fffu + ((x.u >> 16) & 1u)) >> 16);
}
__device__ __forceinline__ float b2f(unsigned short h) {
  union { unsigned u; float f; } x; x.u = ((unsigned)h) << 16;
  return x.f;
}
__device__ __forceinline__ unsigned short bfc(float f) {     // hw cvt (RNE)
  __bf16 h = (__bf16)f;
  return __builtin_bit_cast(unsigned short, h);
}

// ==== PRIMARY prelude, ONE launch ====
// blocks 0..3071:  xpe3[slab][src][rl][h] = bf16(x[src][rl][h] + pe[slab*128+rl][h]),
//                  inp read ONCE, pe computed inline (no peb dependency)
// blocks 3072..3327: top-3 NN (stable, smallest-index ties)
__global__ __launch_bounds__(1024) void k_pre_pri(const float* __restrict__ inp,
                                                  int* __restrict__ idxw,
                                                  unsigned short* __restrict__ xpe) {
  const int b = blockIdx.x;
  const int t = threadIdx.x;
  if (b < 3072) {
    const size_t gid = (size_t)b * 1024 + t;     // 3.146M threads
    const int row = (int)(gid / 96);             // src*128+rl, 0..32767
    const int w8  = (int)(gid - (size_t)row * 96) * 8;
    const int rl  = row & 127;
    const float* px = inp + (size_t)row * NH + w8;
    float4 a = *(const float4*)px;
    float4 bb = *(const float4*)(px + 4);
    float x[8] = {a.x, a.y, a.z, a.w, bb.x, bb.y, bb.z, bb.w};
    const float cc = -0.011992630687355995f;     // (float)(-log(1e4)/768)
    float dv[4];
    #pragma unroll
    for (int j = 0; j < 4; ++j) dv[j] = __expf((float)(w8 + 2 * j) * cc);
    #pragma unroll
    for (int sl = 0; sl < 3; ++sl) {
      const float l = (float)(sl * 128 + rl);
      ushort8 o;
      #pragma unroll
      for (int j = 0; j < 4; ++j) {
        float ang = l * dv[j];
        o[2 * j]     = bfc(x[2 * j]     + sinf(ang));
        o[2 * j + 1] = bfc(x[2 * j + 1] + cosf(ang));
      }
      *(ushort8*)(xpe + ((size_t)sl * 32768 + row) * (size_t)NH + w8) = o;
    }
    return;
  }
  const int i = b - 3072;       // top-3 NN
  __shared__ float xi[772];
  __shared__ float dist[NS];
  __shared__ unsigned long long wkeys[16];
  for (int h = t; h < NH; h += 1024) xi[h + h / 192] = inp[(size_t)i * WH + h];
  __syncthreads();
  const int c = t >> 2, seg = t & 3;
  const float* __restrict__ row = inp + (size_t)c * WH + seg * 192;
  const float* xis = xi + seg * 193;
  float s = 0.f;
  #pragma unroll 4
  for (int h = 0; h < 192; h += 4) {
    float4 v = *(const float4*)(row + h);
    s += fabsf(xis[h]     - v.x) + fabsf(xis[h + 1] - v.y)
       + fabsf(xis[h + 2] - v.z) + fabsf(xis[h + 3] - v.w);
  }
  s += __shfl_xor(s, 1, 64);
  s += __shfl_xor(s, 2, 64);
  if (seg == 0) dist[c] = s;
  __syncthreads();
  for (int k = 0; k < 3; ++k) {
    float d = (t < NS) ? dist[t] : 3.4e38f;
    unsigned long long key = ((unsigned long long)__float_as_uint(d) << 32) | (unsigned)t;
    #pragma unroll
    for (int dd = 1; dd < 64; dd <<= 1) {
      unsigned long long o = __shfl_xor(key, dd, 64);
      key = (o < key) ? o : key;
    }
    if ((t & 63) == 0) wkeys[t >> 6] = key;
    __syncthreads();
    if (t == 0) {
      unsigned long long best = wkeys[0];
      for (int w = 1; w < 16; ++w) if (wkeys[w] < best) best = wkeys[w];
      int bj = (int)(best & 0xffffffffu);
      idxw[i * 3 + k] = bj;
      dist[bj] = 3.4e38f;
    }
    __syncthreads();
  }
}

// ---- fallback launch 1: top3 + PE table ----
__global__ __launch_bounds__(1024) void k_pre1(const float* __restrict__ inp,
                                               int* __restrict__ idxw,
                                               unsigned short* __restrict__ peb) {
  const int t = threadIdx.x;
  const int b = blockIdx.x;
  if (b >= NS) {
    int gid = (b - NS) * 1024 + t;
    int l = gid / NH, d = gid - l * NH;
    const float c = -0.011992630687355995f;
    float dv = __expf((float)(d & ~1) * c);
    float ang = (float)l * dv;
    float v = (d & 1) ? cosf(ang) : sinf(ang);
    peb[gid] = bf16b(v);
    return;
  }
  const int i = b;
  __shared__ float xi[772];
  __shared__ float dist[NS];
  __shared__ unsigned long long wkeys[16];
  for (int h = t; h < NH; h += 1024) xi[h + h / 192] = inp[(size_t)i * WH + h];
  __syncthreads();
  const int c = t >> 2, seg = t & 3;
  const float* __restrict__ row = inp + (size_t)c * WH + seg * 192;
  const float* xis = xi + seg * 193;
  float s = 0.f;
  #pragma unroll 4
  for (int h = 0; h < 192; h += 4) {
    float4 v = *(const float4*)(row + h);
    s += fabsf(xis[h]     - v.x) + fabsf(xis[h + 1] - v.y)
       + fabsf(xis[h + 2] - v.z) + fabsf(xis[h + 3] - v.w);
  }
  s += __shfl_xor(s, 1, 64);
  s += __shfl_xor(s, 2, 64);
  if (seg == 0) dist[c] = s;
  __syncthreads();
  for (int k = 0; k < 3; ++k) {
    float d = (t < NS) ? dist[t] : 3.4e38f;
    unsigned long long key = ((unsigned long long)__float_as_uint(d) << 32) | (unsigned)t;
    #pragma unroll
    for (int dd = 1; dd < 64; dd <<= 1) {
      unsigned long long o = __shfl_xor(key, dd, 64);
      key = (o < key) ? o : key;
    }
    if ((t & 63) == 0) wkeys[t >> 6] = key;
    __syncthreads();
    if (t == 0) {
      unsigned long long best = wkeys[0];
      for (int w = 1; w < 16; ++w) if (wkeys[w] < best) best = wkeys[w];
      int bj = (int)(best & 0xffffffffu);
      idxw[i * 3 + k] = bj;
      dist[bj] = 3.4e38f;
    }
    __syncthreads();
  }
}

// ---- fallback precast ----
__global__ __launch_bounds__(1024) void k_pre_fb(const float* __restrict__ inp,
                                                 unsigned short* __restrict__ inpb) {
  size_t base = ((size_t)blockIdx.x * 1024 + threadIdx.x) * 8;
  float4 a = *(const float4*)(inp + base);
  float4 c = *(const float4*)(inp + base + 4);
  ushort8 o;
  o[0] = bfc(a.x); o[1] = bfc(a.y); o[2] = bfc(a.z); o[3] = bfc(a.w);
  o[4] = bfc(c.x); o[5] = bfc(c.y); o[6] = bfc(c.z); o[7] = bfc(c.w);
  *(ushort8*)(inpb + base) = o;
}

// ==== PRIMARY fused attention (r14, unchanged) ====
__global__ __launch_bounds__(512)
void k_attn(const unsigned short* __restrict__ xpe, const int* __restrict__ idxw,
            float* __restrict__ out) {
  extern __shared__ char smem[];
  unsigned short* Ps = (unsigned short*)smem;              // [128][392] (overlays QK dbuf)
  float* red1 = (float*)(smem + OFF_RED);                  // [128][4]
  float* red2 = red1 + 512;                                // [128][4]
  unsigned short* VT = (unsigned short*)(smem + OFF_VT);   // [64][392]

  const int s = blockIdx.x;
  const int tid = threadIdx.x;
  const int lane = tid & 63, wid = tid >> 6;
  const int lrow = lane & 15, lhi = lane >> 4;
  int idx3[3];
  idx3[0] = idxw[s * 3 + 0]; idx3[1] = idxw[s * 3 + 1]; idx3[2] = idxw[s * 3 + 2];

  const f32x4 fz = {0.f, 0.f, 0.f, 0.f};
  f32x4 acc[4][6];
  #pragma unroll
  for (int qs = 0; qs < 4; ++qs)
    #pragma unroll
    for (int kf = 0; kf < 6; ++kf) acc[qs][kf] = fz;

  const int qh = wid & 1, kq = wid >> 1;     // 64q x 96k per wave
  const int irow0 = wid * 48;
  const int lr8 = lane >> 3, lslot = lane & 7;

  auto issue = [&](int buf, int h0) {
    #pragma unroll
    for (int i = 0; i < 6; ++i) {
      const int row = irow0 + i * 8 + lr8;
      const int slab = row >> 7, rl = row & 127;
      const int cg = lslot ^ (row & 7);                  // source pre-swizzle
      const unsigned short* g = xpe +
          (((size_t)slab * 256 + idx3[slab]) * 128 + rl) * (size_t)NH + h0 + cg * 8;
      __builtin_amdgcn_global_load_lds(AS1(g), AS3(smem + buf * QKBUF + (irow0 + i * 8) * 128),
                                       16, 0, 0);
    }
  };

  issue(0, 0);
  for (int hc = 0; hc < 12; ++hc) {
    const int cur = hc & 1;
    if (hc < 11) {
      issue(cur ^ 1, (hc + 1) * 64);
      asm volatile("s_waitcnt vmcnt(6)" ::: "memory");
    } else {
      asm volatile("s_waitcnt vmcnt(0)" ::: "memory");
    }
    __builtin_amdgcn_s_barrier();
    const unsigned short* Xc = (const unsigned short*)(smem + cur * QKBUF);
    __builtin_amdgcn_s_setprio(1);
    #pragma unroll
    for (int ks = 0; ks < 64; ks += 32) {
      short8 a[4];
      #pragma unroll
      for (int qs = 0; qs < 4; ++qs) {
        const int ar = qh * 64 + qs * 16 + lrow;
        a[qs] = *reinterpret_cast<const short8*>(
            &Xc[ar * 64 + ((((ks >> 3) + lhi) ^ (ar & 7)) << 3)]);
      }
      #pragma unroll
      for (int kf = 0; kf < 6; ++kf) {
        const int br = kq * 96 + kf * 16 + lrow;
        short8 b = *reinterpret_cast<const short8*>(
            &Xc[br * 64 + ((((ks >> 3) + lhi) ^ (br & 7)) << 3)]);
        #pragma unroll
        for (int qs = 0; qs < 4; ++qs)
          acc[qs][kf] = __builtin_amdgcn_mfma_f32_16x16x32_bf16(a[qs], b, acc[qs][kf], 0, 0, 0);
      }
    }
    __builtin_amdgcn_s_setprio(0);
    __builtin_amdgcn_s_barrier();
  }

  const float scale = 0.03608439182435161f;  // 1/sqrt(768)
  float mx[4][4];
  #pragma unroll
  for (int qs = 0; qs < 4; ++qs)
    #pragma unroll
    for (int r = 0; r < 4; ++r) {
      float m = acc[qs][0][r];
      #pragma unroll
      for (int kf = 1; kf < 6; ++kf) m = fmaxf(m, acc[qs][kf][r]);
      #pragma unroll
      for (int d = 1; d < 16; d <<= 1) m = fmaxf(m, __shfl_xor(m, d, 64));
      mx[qs][r] = m;
    }
  if (lrow == 0) {
    #pragma unroll
    for (int qs = 0; qs < 4; ++qs)
      #pragma unroll
      for (int r = 0; r < 4; ++r)
        red1[(qh * 64 + qs * 16 + lhi * 4 + r) * 4 + kq] = mx[qs][r];
  }
  __syncthreads();
  float sm[4][4];
  #pragma unroll
  for (int qs = 0; qs < 4; ++qs)
    #pragma unroll
    for (int r = 0; r < 4; ++r) {
      const int row = qh * 64 + qs * 16 + lhi * 4 + r;
      float4 m0 = *(const float4*)&red1[row * 4];
      mx[qs][r] = fmaxf(fmaxf(m0.x, m0.y), fmaxf(m0.z, m0.w));
      sm[qs][r] = 0.f;
    }
  #pragma unroll
  for (int qs = 0; qs < 4; ++qs)
    #pragma unroll
    for (int kf = 0; kf < 6; ++kf)
      #pragma unroll
      for (int r = 0; r < 4; ++r) {
        float p = __expf((acc[qs][kf][r] - mx[qs][r]) * scale);
        acc[qs][kf][r] = p;
        sm[qs][r] += p;
      }
  #pragma unroll
  for (int qs = 0; qs < 4; ++qs)
    #pragma unroll
    for (int r = 0; r < 4; ++r) {
      #pragma unroll
      for (int d = 1; d < 16; d <<= 1) sm[qs][r] += __shfl_xor(sm[qs][r], d, 64);
    }
  if (lrow == 0) {
    #pragma unroll
    for (int qs = 0; qs < 4; ++qs)
      #pragma unroll
      for (int r = 0; r < 4; ++r)
        red2[(qh * 64 + qs * 16 + lhi * 4 + r) * 4 + kq] = sm[qs][r];
  }
  __syncthreads();
  #pragma unroll
  for (int qs = 0; qs < 4; ++qs)
    #pragma unroll
    for (int r = 0; r < 4; ++r) {
      const int row = qh * 64 + qs * 16 + lhi * 4 + r;
      float4 s0 = *(const float4*)&red2[row * 4];
      sm[qs][r] = 1.0f / ((s0.x + s0.y) + (s0.z + s0.w));
    }
  #pragma unroll
  for (int qs = 0; qs < 4; ++qs)
    #pragma unroll
    for (int kf = 0; kf < 6; ++kf)
      #pragma unroll
      for (int r = 0; r < 4; ++r) {
        const int row = qh * 64 + qs * 16 + lhi * 4 + r;
        const int col = kq * 96 + kf * 16 + lrow;
        *(unsigned short*)((char*)Ps + (((row * PS_STRIDE + col) * 2) ^ (((row >> 3) & 7) << 4))) =
            bfc(acc[qs][kf][r] * sm[qs][r]);
      }
  __syncthreads();

  const int qb = wid & 3, hh = wid >> 2;
  short8 pa[2][12];
  #pragma unroll
  for (int qs = 0; qs < 2; ++qs)
    #pragma unroll
    for (int m0 = 0; m0 < 12; ++m0) {
      const int row = qb * 32 + qs * 16 + lrow;
      pa[qs][m0] = *reinterpret_cast<const short8*>(
          (const char*)Ps + (((row * PS_STRIDE + m0 * 32 + lhi * 8) * 2) ^ (((row >> 3) & 7) << 4)));
    }
  const int rl0 = tid >> 3, c8 = (tid & 7) * 8;
  for (int t4 = 0; t4 < 12; ++t4) {
    const int h0 = t4 * 64;
    #pragma unroll
    for (int it = 0; it < 6; ++it) {
      const int slab = it >> 1;
      const int ml = rl0 + (it & 1) * 64;
      const int m  = ml + slab * 128;
      ushort8 xv = *(const ushort8*)&xpe[(((size_t)slab * 256 + idx3[slab]) * 128 + ml) * (size_t)NH + h0 + c8];
      #pragma unroll
      for (int j = 0; j < 8; ++j) {
        const int vr = c8 + j;
        VT[((vr * PS_STRIDE) + m) ^ (((vr >> 3) & 7) << 3)] = xv[j];
      }
    }
    __syncthreads();
    __builtin_amdgcn_s_setprio(1);
    f32x4 o00 = fz, o01 = fz, o10 = fz, o11 = fz;
    const int vr0 = hh * 32 + lrow, vr1 = vr0 + 16;
    const int sw0 = ((vr0 >> 3) & 7) << 4, sw1 = ((vr1 >> 3) & 7) << 4;
    #pragma unroll
    for (int mm = 0; mm < 12; ++mm) {
      const int moff = (mm * 32 + lhi * 8) * 2;
      short8 b0 = *reinterpret_cast<const short8*>((const char*)VT + ((vr0 * PS_STRIDE * 2 + moff) ^ sw0));
      short8 b1 = *reinterpret_cast<const short8*>((const char*)VT + ((vr1 * PS_STRIDE * 2 + moff) ^ sw1));
      o00 = __builtin_amdgcn_mfma_f32_16x16x32_bf16(pa[0][mm], b0, o00, 0, 0, 0);
      o01 = __builtin_amdgcn_mfma_f32_16x16x32_bf16(pa[0][mm], b1, o01, 0, 0, 0);
      o10 = __builtin_amdgcn_mfma_f32_16x16x32_bf16(pa[1][mm], b0, o10, 0, 0, 0);
      o11 = __builtin_amdgcn_mfma_f32_16x16x32_bf16(pa[1][mm], b1, o11, 0, 0, 0);
    }
    __builtin_amdgcn_s_setprio(0);
    float* ob = out + (size_t)s * (OUTROWS * NH) + h0 + hh * 32 + lrow;
    #pragma unroll
    for (int qs = 0; qs < 2; ++qs)
      #pragma unroll
      for (int hf = 0; hf < 2; ++hf) {
        f32x4 o = (qs == 0) ? (hf == 0 ? o00 : o01) : (hf == 0 ? o10 : o11);
        #pragma unroll
        for (int r = 0; r < 4; ++r) {
          const int q = qb * 32 + qs * 16 + lhi * 4 + r;
          if (q < OUTROWS) ob[(size_t)q * NH + hf * 16] = o[r];
        }
      }
    __syncthreads();
  }
}

// ==== FALLBACK fused attention (r8 verbatim) ====
__global__ __launch_bounds__(512)
void k_attn_fb(const unsigned short* __restrict__ inpb, const unsigned short* __restrict__ peb,
               const int* __restrict__ idxw, float* __restrict__ out) {
  extern __shared__ char smem[];
  unsigned short* Xs = (unsigned short*)smem;
  unsigned short* Ps = (unsigned short*)(smem + FB_SMEM_PS);
  float* red1 = (float*)(smem + FB_SMEM_RED);
  float* red2 = red1 + 512;

  const int s = blockIdx.x;
  const int tid = threadIdx.x;
  const int lane = tid & 63, wid = tid >> 6;
  const int lrow = lane & 15, lhi = lane >> 4;
  const int i0 = idxw[s * 3 + 0], i1 = idxw[s * 3 + 1], i2 = idxw[s * 3 + 2];

  const f32x4 fz = {0.f, 0.f, 0.f, 0.f};
  f32x4 acc[4][6];
  #pragma unroll
  for (int qs = 0; qs < 4; ++qs)
    #pragma unroll
    for (int kf = 0; kf < 6; ++kf) acc[qs][kf] = fz;

  const int qh = wid & 1, kq = wid >> 1;
  for (int hc = 0; hc < 6; ++hc) {
    const int h0 = hc * 128;
    #pragma unroll
    for (int it = 0; it < 12; ++it) {
      const int src = (it < 4) ? i0 : (it < 8 ? i1 : i2);
      const int rls = (it & 3) * 32 + (tid >> 4);
      const int r   = it * 32 + (tid >> 4);
      const int cc  = (tid & 15) * 8;
      ushort8 xv = *(const ushort8*)&inpb[(size_t)src * WH + (size_t)rls * NH + h0 + cc];
      ushort8 pv = *(const ushort8*)&peb[r * NH + h0 + cc];
      bf16x8 o;
      #pragma unroll
      for (int j = 0; j < 8; ++j) o[j] = (__bf16)(b2f(xv[j]) + b2f(pv[j]));
      *reinterpret_cast<bf16x8*>(&Xs[r * XS2_STRIDE + cc]) = o;
    }
    __syncthreads();
    __builtin_amdgcn_s_setprio(1);
    #pragma unroll
    for (int ks = 0; ks < 128; ks += 32) {
      short8 a[4];
      #pragma unroll
      for (int qs = 0; qs < 4; ++qs)
        a[qs] = *reinterpret_cast<const short8*>(&Xs[(qh * 64 + qs * 16 + lrow) * XS2_STRIDE + ks + lhi * 8]);
      #pragma unroll
      for (int kf = 0; kf < 6; ++kf) {
        short8 b = *reinterpret_cast<const short8*>(&Xs[(kq * 96 + kf * 16 + lrow) * XS2_STRIDE + ks + lhi * 8]);
        #pragma unroll
        for (int qs = 0; qs < 4; ++qs)
          acc[qs][kf] = __builtin_amdgcn_mfma_f32_16x16x32_bf16(a[qs], b, acc[qs][kf], 0, 0, 0);
      }
    }
    __builtin_amdgcn_s_setprio(0);
    __syncthreads();
  }
  const float scale = 0.03608439182435161f;
  float mx[4][4];
  #pragma unroll
  for (int qs = 0; qs < 4; ++qs)
    #pragma unroll
    for (int r = 0; r < 4; ++r) {
      float m = acc[qs][0][r];
      #pragma unroll
      for (int kf = 1; kf < 6; ++kf) m = fmaxf(m, acc[qs][kf][r]);
      #pragma unroll
      for (int d = 1; d < 16; d <<= 1) m = fmaxf(m, __shfl_xor(m, d, 64));
      mx[qs][r] = m;
    }
  if (lrow == 0) {
    #pragma unroll
    for (int qs = 0; qs < 4; ++qs)
      #pragma unroll
      for (int r = 0; r < 4; ++r)
        red1[(qh * 64 + qs * 16 + lhi * 4 + r) * 4 + kq] = mx[qs][r];
  }
  __syncthreads();
  float sm[4][4];
  #pragma unroll
  for (int qs = 0; qs < 4; ++qs)
    #pragma unroll
    for (int r = 0; r < 4; ++r) {
      const int row = qh * 64 + qs * 16 + lhi * 4 + r;
      float4 m0 = *(const float4*)&red1[row * 4];
      mx[qs][r] = fmaxf(fmaxf(m0.x, m0.y), fmaxf(m0.z, m0.w));
      sm[qs][r] = 0.f;
    }
  #pragma unroll
  for (int qs = 0; qs < 4; ++qs)
    #pragma unroll
    for (int kf = 0; kf < 6; ++kf)
      #pragma unroll
      for (int r = 0; r < 4; ++r) {
        float p = __expf((acc[qs][kf][r] - mx[qs][r]) * scale);
        acc[qs][kf][r] = p;
        sm[qs][r] += p;
      }
  #pragma unroll
  for (int qs = 0; qs < 4; ++qs)
    #pragma unroll
    for (int r = 0; r < 4; ++r) {
      #pragma unroll
      for (int d = 1; d < 16; d <<= 1) sm[qs][r] += __shfl_xor(sm[qs][r], d, 64);
    }
  if (lrow == 0) {
    #pragma unroll
    for (int qs = 0; qs < 4; ++qs)
      #pragma unroll
      for (int r = 0; r < 4; ++r)
        red2[(qh * 64 + qs * 16 + lhi * 4 + r) * 4 + kq] = sm[qs][r];
  }
  __syncthreads();
  #pragma unroll
  for (int qs = 0; qs < 4; ++qs)
    #pragma unroll
    for (int r = 0; r < 4; ++r) {
      const int row = qh * 64 + qs * 16 + lhi * 4 + r;
      float4 s0 = *(const float4*)&red2[row * 4];
      sm[qs][r] = 1.0f / ((s0.x + s0.y) + (s0.z + s0.w));
    }
  #pragma unroll
  for (int qs = 0; qs < 4; ++qs)
    #pragma unroll
    for (int kf = 0; kf < 6; ++kf)
      #pragma unroll
      for (int r = 0; r < 4; ++r) {
        const int row = qh * 64 + qs * 16 + lhi * 4 + r;
        const int col = kq * 96 + kf * 16 + lrow;
        *(unsigned short*)((char*)Ps + (((row * PS_STRIDE + col) * 2) ^ (((row >> 3) & 7) << 4))) =
            bfc(acc[qs][kf][r] * sm[qs][r]);
      }
  __syncthreads();
  const int qb = wid & 3, hh = wid >> 2;
  short8 pa[2][12];
  #pragma unroll
  for (int qs = 0; qs < 2; ++qs)
    #pragma unroll
    for (int m0 = 0; m0 < 12; ++m0) {
      const int row = qb * 32 + qs * 16 + lrow;
      pa[qs][m0] = *reinterpret_cast<const short8*>(
          (const char*)Ps + (((row * PS_STRIDE + m0 * 32 + lhi * 8) * 2) ^ (((row >> 3) & 7) << 4)));
    }
  unsigned short* VT = Xs;
  const int rl0 = tid >> 3, c8 = (tid & 7) * 8;
  for (int t4 = 0; t4 < 12; ++t4) {
    const int h0 = t4 * 64;
    #pragma unroll
    for (int it = 0; it < 6; ++it) {
      const int src = (it < 2) ? i0 : (it < 4 ? i1 : i2);
      const int ml = rl0 + (it & 1) * 64;
      const int m  = ml + (it >> 1) * 128;
      ushort8 xv = *(const ushort8*)&inpb[(size_t)src * WH + (size_t)ml * NH + h0 + c8];
      ushort8 pv = *(const ushort8*)&peb[m * NH + h0 + c8];
      #pragma unroll
      for (int j = 0; j < 8; ++j) {
        const int vr = c8 + j;
        VT[((vr * PS_STRIDE) + m) ^ (((vr >> 3) & 7) << 3)] = bfc(b2f(xv[j]) + b2f(pv[j]));
      }
    }
    __syncthreads();
    __builtin_amdgcn_s_setprio(1);
    f32x4 o00 = fz, o01 = fz, o10 = fz, o11 = fz;
    const int vr0 = hh * 32 + lrow, vr1 = vr0 + 16;
    const int sw0 = ((vr0 >> 3) & 7) << 4, sw1 = ((vr1 >> 3) & 7) << 4;
    #pragma unroll
    for (int mm = 0; mm < 12; ++mm) {
      const int moff = (mm * 32 + lhi * 8) * 2;
      short8 b0 = *reinterpret_cast<const short8*>((const char*)VT + ((vr0 * PS_STRIDE * 2 + moff) ^ sw0));
      short8 b1 = *reinterpret_cast<const short8*>((const char*)VT + ((vr1 * PS_STRIDE * 2 + moff) ^ sw1));
      o00 = __builtin_amdgcn_mfma_f32_16x16x32_bf16(pa[0][mm], b0, o00, 0, 0, 0);
      o01 = __builtin_amdgcn_mfma_f32_16x16x32_bf16(pa[0][mm], b1, o01, 0, 0, 0);
      o10 = __builtin_amdgcn_mfma_f32_16x16x32_bf16(pa[1][mm], b0, o10, 0, 0, 0);
      o11 = __builtin_amdgcn_mfma_f32_16x16x32_bf16(pa[1][mm], b1, o11, 0, 0, 0);
    }
    __builtin_amdgcn_s_setprio(0);
    float* ob = out + (size_t)s * (OUTROWS * NH) + h0 + hh * 32 + lrow;
    #pragma unroll
    for (int qs = 0; qs < 2; ++qs)
      #pragma unroll
      for (int hf = 0; hf < 2; ++hf) {
        f32x4 o = (qs == 0) ? (hf == 0 ? o00 : o01) : (hf == 0 ? o10 : o11);
        #pragma unroll
        for (int r = 0; r < 4; ++r) {
          const int q = qb * 32 + qs * 16 + lhi * 4 + r;
          if (q < OUTROWS) ob[(size_t)q * NH + hf * 16] = o[r];
        }
      }
    __syncthreads();
  }
}

// ---------------- launch ----------------
extern "C" void kernel_launch(void* const* d_in, const int* in_sizes, int n_in,
                              void* d_out, int out_size, void* d_ws, size_t ws_size,
                              hipStream_t stream) {
  (void)in_sizes; (void)n_in; (void)out_size;
  const float* inp = (const float*)d_in[0];
  float* out = (float*)d_out;
  char* ws = (char*)d_ws;

  unsigned short* peb = (unsigned short*)ws;                     // 589824 B (fallback only)
  int* idxw           = (int*)(ws + 589824);                     // 3072 B
  unsigned short* big = (unsigned short*)(ws + 592896);          // xpe3 (151MB) or inpb (50MB)
  const bool primary = ws_size >= (size_t)592896 + (size_t)150994944;

  if (primary) {
    hipLaunchKernelGGL(k_pre_pri, dim3(3328), dim3(1024), 0, stream, inp, idxw, big);
    hipFuncSetAttribute((const void*)k_attn,
                        hipFuncAttributeMaxDynamicSharedMemorySize, SMEM_PRI);
    hipLaunchKernelGGL(k_attn, dim3(256), dim3(512), SMEM_PRI, stream, big, idxw, out);
  } else {
    hipLaunchKernelGGL(k_pre1, dim3(544), dim3(1024), 0, stream, inp, idxw, peb);
    hipLaunchKernelGGL(k_pre_fb, dim3(3072), dim3(1024), 0, stream, inp, big);
    hipFuncSetAttribute((const void*)k_attn_fb,
                        hipFuncAttributeMaxDynamicSharedMemorySize, FB_SMEM_TOTAL);
    hipLaunchKernelGGL(k_attn_fb, dim3(256), dim3(512), FB_SMEM_TOTAL, stream,
                       big, peb, idxw, out);
  }
}